// Round 9
// baseline (1912.998 us; speedup 1.0000x reference)
//
#include <hip/hip_runtime.h>
#include <math.h>

#define NB 8
#define NN 2048
#define NM 2048
#define NITERS 50

static constexpr float LOG2E  = 1.4426950408889634f;
static constexpr float KK     = LOG2E / 0.005f;     // 288.539...
static constexpr float TWOK   = 2.0f * KK;
static constexpr float NEG_LOG2N = -11.0f;          // -log2(2048)

__device__ __forceinline__ float fexp2(float x) { return __builtin_amdgcn_exp2f(x); }
__device__ __forceinline__ float flog2(float x) { return __builtin_amdgcn_logf(x); }

// sc1 (agent-coherent, L3-direct) accesses via relaxed atomics: no fences.
__device__ __forceinline__ float ld_sc1(const float* p) {
    return __hip_atomic_load(p, __ATOMIC_RELAXED, __HIP_MEMORY_SCOPE_AGENT);
}
__device__ __forceinline__ void st_sc1(float* p, float v) {
    __hip_atomic_store(p, v, __ATOMIC_RELAXED, __HIP_MEMORY_SCOPE_AGENT);
}

struct SmemT {
    float2 part [16][257];   // [row][partial 0..255]
    float2 part2[16][17];    // [row][seg]
    float  wsum[4];
};

// ---------------------------------------------------------------------------
// Fence-free per-batch barrier (128 WGs/batch, one flag word per WG).
// Writer path: explicit vmcnt(0) drains this thread's sc1 D-stores (sc1
// retire = visible at L3), then tid0 stores its flag (relaxed, sc1).
// Readers: wave0 polls all 128 flags with relaxed sc1 loads (no cached
// data can go stale: everything mutable is sc1-only). No wbl2/inv ever.
// ---------------------------------------------------------------------------
__device__ __forceinline__ void flag_barrier(int* __restrict__ fb, int wgb, int phase)
{
    asm volatile("s_waitcnt vmcnt(0)" ::: "memory");
    __syncthreads();
    if (threadIdx.x == 0)
        __hip_atomic_store(fb + wgb, phase, __ATOMIC_RELAXED, __HIP_MEMORY_SCOPE_AGENT);
    if (threadIdx.x < 64) {
        const int l = threadIdx.x;
        for (;;) {
            const int a = __hip_atomic_load(fb + l,      __ATOMIC_RELAXED, __HIP_MEMORY_SCOPE_AGENT);
            const int c = __hip_atomic_load(fb + l + 64, __ATOMIC_RELAXED, __HIP_MEMORY_SCOPE_AGENT);
            if (__all((a >= phase) && (c >= phase))) break;
            __builtin_amdgcn_s_sleep(2);
        }
    }
    __syncthreads();
}

// ---------------------------------------------------------------------------
// One half-sweep for this WG's 16 rows over all 2048 opposite points.
// Wave = m-quarter, lane = 8 m's (stride 64). Static Q cached; dynamic D sc1.
// z = D_m + fmaf(xs0,Q.x, fmaf(xs1,Q.y, fmaf(xs2,Q.z, Q.w)))  [Q.w = -K|u|^2]
// Streaming chunk-4 LSE identical to the verified absmax-0.0 kernels.
// ---------------------------------------------------------------------------
__device__ __forceinline__ void half_sweep(
    const float4* __restrict__ Qin_b,   // opposite static + b*NM
    const float*  __restrict__ Din_b,   // opposite dynamic + b*NM (sc1)
    const float4* __restrict__ Qrow,    // own static + b*NN + rowbase
    float*        __restrict__ Drow,    // own dynamic out + b*NN + rowbase (sc1)
    SmemT& sm)
{
    const int tid  = threadIdx.x;
    const int lane = tid & 63;
    const int wave = tid >> 6;

    float xs0[16], xs1[16], xs2[16];
    #pragma unroll
    for (int r = 0; r < 16; ++r) {
        const float4 q = Qrow[r];
        xs0[r] = TWOK * q.x; xs1[r] = TWOK * q.y; xs2[r] = TWOK * q.z;
    }

    const float4* __restrict__ qq = Qin_b + wave * 512 + lane;
    const float*  __restrict__ dd = Din_b + wave * 512 + lane;

    float rm[16], rs[16];
    #pragma unroll
    for (int r = 0; r < 16; ++r) { rm[r] = -1e30f; rs[r] = 0.f; }

    #pragma unroll
    for (int ib = 0; ib < 2; ++ib) {
        const float  d0 = ld_sc1(dd + (ib*4 + 0) * 64);
        const float  d1 = ld_sc1(dd + (ib*4 + 1) * 64);
        const float  d2 = ld_sc1(dd + (ib*4 + 2) * 64);
        const float  d3 = ld_sc1(dd + (ib*4 + 3) * 64);
        const float4 c0 = qq[(ib*4 + 0) * 64];
        const float4 c1 = qq[(ib*4 + 1) * 64];
        const float4 c2 = qq[(ib*4 + 2) * 64];
        const float4 c3 = qq[(ib*4 + 3) * 64];
        #pragma unroll
        for (int r = 0; r < 16; ++r) {
            const float z0 = d0 + fmaf(xs0[r], c0.x, fmaf(xs1[r], c0.y, fmaf(xs2[r], c0.z, c0.w)));
            const float z1 = d1 + fmaf(xs0[r], c1.x, fmaf(xs1[r], c1.y, fmaf(xs2[r], c1.z, c1.w)));
            const float z2 = d2 + fmaf(xs0[r], c2.x, fmaf(xs1[r], c2.y, fmaf(xs2[r], c2.z, c2.w)));
            const float z3 = d3 + fmaf(xs0[r], c3.x, fmaf(xs1[r], c3.y, fmaf(xs2[r], c3.z, c3.w)));
            const float cm = fmaxf(fmaxf(z0, z1), fmaxf(z2, z3));
            const float nm = fmaxf(rm[r], cm);
            const float s  = (fexp2(z0 - nm) + fexp2(z1 - nm))
                           + (fexp2(z2 - nm) + fexp2(z3 - nm));
            rs[r] = fmaf(rs[r], fexp2(rm[r] - nm), s);
            rm[r] = nm;
        }
    }

    #pragma unroll
    for (int r = 0; r < 16; ++r)
        sm.part[r][tid] = make_float2(rm[r], rs[r]);
    __syncthreads();

    {   // stage 2: thread (row=tid&15, seg=tid>>4) folds 16 partials
        const int row = tid & 15, seg = tid >> 4;
        float m16 = -1e30f;
        float2 v[16];
        #pragma unroll
        for (int k = 0; k < 16; ++k) { v[k] = sm.part[row][seg*16 + k]; m16 = fmaxf(m16, v[k].x); }
        float s16 = 0.f;
        #pragma unroll
        for (int k = 0; k < 16; ++k) s16 = fmaf(v[k].y, fexp2(v[k].x - m16), s16);
        sm.part2[row][seg] = make_float2(m16, s16);
    }
    __syncthreads();

    if (tid < 16) {   // stage 3: fold 16 segs, write dynamic dual (sc1)
        float gm = -1e30f;
        float2 v[16];
        #pragma unroll
        for (int k = 0; k < 16; ++k) { v[k] = sm.part2[tid][k]; gm = fmaxf(gm, v[k].x); }
        float s = 0.f;
        #pragma unroll
        for (int k = 0; k < 16; ++k) s = fmaf(v[k].y, fexp2(v[k].x - gm), s);
        const float lse2 = gm + flog2(s);
        // D = K*dual = NEG_LOG2N - lse2 + K|v|^2   (Q.w = -K|v|^2)
        st_sc1(Drow + tid, NEG_LOG2N - lse2 - Qrow[tid].w);
    }
    __syncthreads();
}

// ---------------------------------------------------------------------------
// Persistent kernel: init -> 50x (f-half, bar, g-half, bar) -> final loss.
// grid = 1024 WGs x 256 thr = 4 WG/CU, all co-resident (proven by R5/R6).
// batch = blockIdx&7: under round-robin XCD dispatch, each batch is
// XCD-local (perf only; correctness from sc1 protocol above).
// ---------------------------------------------------------------------------
__global__ __launch_bounds__(256, 4) void sinkhorn_all(
    const float* __restrict__ X, const float* __restrict__ Y,
    float4* __restrict__ Qx, float4* __restrict__ Qy,
    float* __restrict__ Dx, float* __restrict__ Dy,
    int* __restrict__ flags, float* __restrict__ out)
{
    __shared__ SmemT sm;
    const int tid     = threadIdx.x;
    const int b       = blockIdx.x & 7;
    const int wgb     = blockIdx.x >> 3;       // 0..127 within batch
    const int rowbase = wgb * 16;
    int* fb = flags + b * 128;

    // ---- init my 16 rows, both sides: static Q (sc1 stores, read cached
    //      only after the barrier) + dynamic D = 0.
    if (tid < 32) {
        const int r   = tid & 15;
        const int row = rowbase + r;
        if (tid < 16) {
            const float* vp = X + (size_t)(b * NN + row) * 3;
            const float v0 = vp[0], v1 = vp[1], v2 = vp[2];
            const float sq = fmaf(v0, v0, fmaf(v1, v1, v2 * v2));
            float4* q = Qx + b * NN + row;
            st_sc1(&q->x, v0); st_sc1(&q->y, v1); st_sc1(&q->z, v2); st_sc1(&q->w, -KK * sq);
            st_sc1(Dx + b * NN + row, 0.f);
        } else {
            const float* vp = Y + (size_t)(b * NM + row) * 3;
            const float v0 = vp[0], v1 = vp[1], v2 = vp[2];
            const float sq = fmaf(v0, v0, fmaf(v1, v1, v2 * v2));
            float4* q = Qy + b * NM + row;
            st_sc1(&q->x, v0); st_sc1(&q->y, v1); st_sc1(&q->z, v2); st_sc1(&q->w, -KK * sq);
            st_sc1(Dy + b * NM + row, 0.f);
        }
    }

    int phase = 1;
    flag_barrier(fb, wgb, phase);

    const float4* QxB = Qx + b * NN;
    const float4* QyB = Qy + b * NM;
    float* DxB = Dx + b * NN;
    float* DyB = Dy + b * NM;

    #pragma unroll 1
    for (int it = 0; it < NITERS; ++it) {
        half_sweep(QyB, DyB, QxB + rowbase, DxB + rowbase, sm);   // f-update
        flag_barrier(fb, wgb, ++phase);
        half_sweep(QxB, DxB, QyB + rowbase, DyB + rowbase, sm);   // g-update
        flag_barrier(fb, wgb, ++phase);
    }

    // ---- final loss over my 16 x-rows x all 2048 m
    {
        const int lane = tid & 63;
        const int wave = tid >> 6;

        float xr0[16], xr1[16], xr2[16], Afv[16], xq[16];
        const float4* xb  = QxB + rowbase;
        const float*  dxb = DxB + rowbase;
        #pragma unroll
        for (int r = 0; r < 16; ++r) {
            const float4 q = xb[r];
            xr0[r] = q.x; xr1[r] = q.y; xr2[r] = q.z;
            xq[r]  = fmaf(q.x, q.x, fmaf(q.y, q.y, q.z * q.z));
            Afv[r] = ld_sc1(dxb + r) + q.w;        // K(f - |x|^2)
        }

        const float4* __restrict__ qq = QyB + wave * 512 + lane;
        const float*  __restrict__ dd = DyB + wave * 512 + lane;

        float acc = 0.f;
        #pragma unroll
        for (int i = 0; i < 8; ++i) {
            const float4 p  = qq[i * 64];
            const float  Ag = ld_sc1(dd + i * 64) + p.w;   // K(g - |y|^2)
            const float ysq = fmaf(p.x, p.x, fmaf(p.y, p.y, p.z * p.z));
            #pragma unroll
            for (int r = 0; r < 16; ++r) {
                const float dot = fmaf(xr0[r], p.x, fmaf(xr1[r], p.y, xr2[r] * p.z));
                const float cc  = fmaxf(fmaf(-2.f, dot, xq[r] + ysq), 0.f);
                const float zp  = fmaf(TWOK, dot, Afv[r] + Ag);
                acc = fmaf(fexp2(zp), cc, acc);
            }
        }
        #pragma unroll
        for (int o = 32; o > 0; o >>= 1) acc += __shfl_xor(acc, o);
        if (lane == 0) sm.wsum[wave] = acc;
        __syncthreads();
        if (tid == 0) {
            atomicAdd(out, (sm.wsum[0] + sm.wsum[1] + sm.wsum[2] + sm.wsum[3]) * (1.0f / NB));
        }
    }
}

// ---------------------------------------------------------------------------
extern "C" void kernel_launch(void* const* d_in, const int* in_sizes, int n_in,
                              void* d_out, int out_size, void* d_ws, size_t ws_size,
                              hipStream_t stream)
{
    const float* x = (const float*)d_in[0];
    const float* y = (const float*)d_in[1];
    float4* Qx = (float4*)d_ws;                 // [B][N] static packed x
    float4* Qy = Qx + NB * NN;                  // [B][M] static packed y
    float*  Dx = (float*)(Qy + NB * NM);        // [B][N] dynamic K*f
    float*  Dy = Dx + NB * NN;                  // [B][M] dynamic K*g
    int* flags = (int*)(Dy + NB * NM);          // [B][128] barrier flags

    hipMemsetAsync(flags, 0, NB * 128 * sizeof(int), stream);
    hipMemsetAsync(d_out, 0, sizeof(float), stream);

    sinkhorn_all<<<NB * NN / 16, 256, 0, stream>>>(x, y, Qx, Qy, Dx, Dy, flags, (float*)d_out);
}